// Round 1
// baseline (555.323 us; speedup 1.0000x reference)
//
#include <hip/hip_runtime.h>

// -------------------- helpers --------------------
static __device__ __forceinline__ float4 ld4(const float* p) { return *(const float4*)p; }

// -------------------- setup kernels --------------------
__global__ __launch_bounds__(256) void k_init(float* deg, int* cnt, int* fill, int n) {
    int i = blockIdx.x * 256 + threadIdx.x;
    if (i < n) { deg[i] = 1.0f; cnt[i] = 0; fill[i] = 0; }
}

__global__ __launch_bounds__(256) void k_edge_count(const int* __restrict__ dst,
                                                    const float* __restrict__ ew,
                                                    float* deg, int* cnt, int E) {
    int e = blockIdx.x * 256 + threadIdx.x;
    if (e < E) {
        int d = dst[e];
        atomicAdd(&deg[d], ew[e]);
        atomicAdd(&cnt[d], 1);
    }
}

__global__ __launch_bounds__(256) void k_dinv(const float* __restrict__ deg, float* dinv, int n) {
    int i = blockIdx.x * 256 + threadIdx.x;
    if (i < n) dinv[i] = rsqrtf(deg[i]);   // deg >= 1 always (self-loop)
}

// -------------------- 3-phase exclusive scan over cnt -> rowptr --------------------
__global__ __launch_bounds__(256) void k_scan_local(const int* __restrict__ cnt,
                                                    int* __restrict__ rowptr,
                                                    int* __restrict__ bsum, int n) {
    __shared__ int s[256];
    int tid = threadIdx.x;
    int i = blockIdx.x * 256 + tid;
    int v = (i < n) ? cnt[i] : 0;
    s[tid] = v; __syncthreads();
    #pragma unroll
    for (int off = 1; off < 256; off <<= 1) {
        int t = (tid >= off) ? s[tid - off] : 0;
        __syncthreads();
        s[tid] += t;
        __syncthreads();
    }
    if (i < n) rowptr[i] = s[tid] - v;          // block-local exclusive
    if (tid == 255) bsum[blockIdx.x] = s[255];  // block total
}

__global__ __launch_bounds__(256) void k_scan_bsum(int* bsum, int nb) {
    __shared__ int s[256];
    __shared__ int run;
    int tid = threadIdx.x;
    if (tid == 0) run = 0;
    __syncthreads();
    for (int base = 0; base < nb; base += 256) {
        int v = (base + tid < nb) ? bsum[base + tid] : 0;
        s[tid] = v; __syncthreads();
        #pragma unroll
        for (int off = 1; off < 256; off <<= 1) {
            int t = (tid >= off) ? s[tid - off] : 0;
            __syncthreads();
            s[tid] += t;
            __syncthreads();
        }
        if (base + tid < nb) bsum[base + tid] = run + s[tid] - v;
        __syncthreads();
        if (tid == 0) run += s[255];
        __syncthreads();
    }
}

__global__ __launch_bounds__(256) void k_scan_add(int* __restrict__ rowptr,
                                                  const int* __restrict__ bsum, int n) {
    int i = blockIdx.x * 256 + threadIdx.x;
    if (i < n) rowptr[i] += bsum[blockIdx.x];
}

// -------------------- scatter edges into CSR (by dst) --------------------
__global__ __launch_bounds__(256) void k_scatter(const int* __restrict__ src,
                                                 const int* __restrict__ dst,
                                                 const float* __restrict__ ew,
                                                 const float* __restrict__ dinv,
                                                 const int* __restrict__ rowptr,
                                                 int* fill,
                                                 int* __restrict__ csr_src,
                                                 float* __restrict__ csr_norm, int E) {
    int e = blockIdx.x * 256 + threadIdx.x;
    if (e < E) {
        int s = src[e], d = dst[e];
        int p = rowptr[d] + atomicAdd(&fill[d], 1);
        csr_src[p] = s;
        csr_norm[p] = dinv[s] * ew[e] * dinv[d];
    }
}

// -------------------- GEMM: out[n,64] = A[n,K] @ W[K,64] --------------------
// Block tile 64 rows x 64 cols, thread micro-tile 4x4, W and X in LDS, float4 reads.
// SPLITW: W assembled from two [K,32] matrices (W_mu | W_lv).
template<int K, bool SPLITW>
__global__ __launch_bounds__(256) void k_gemm(const float* __restrict__ A,
                                              const float* __restrict__ W0,
                                              const float* __restrict__ W1s,
                                              float* __restrict__ out, int n) {
    __shared__ float Ws[K * 64];
    __shared__ float Xs[64 * K];
    int tid = threadIdx.x;
    int row0 = blockIdx.x * 64;

    // stage W (K*64 floats)
    constexpr int WF4 = K * 64 / 4;
    for (int j = tid; j < WF4; j += 256) {
        float4 v;
        if (!SPLITW) {
            v = ld4(W0 + j * 4);
        } else {
            int k = (j * 4) >> 6;
            int c = (j * 4) & 63;
            v = (c < 32) ? ld4(W0 + k * 32 + c) : ld4(W1s + k * 32 + (c - 32));
        }
        *(float4*)&Ws[j * 4] = v;
    }
    // stage X (64 rows x K)
    constexpr int XF4PR = K / 4;
    for (int j = tid; j < 64 * XF4PR; j += 256) {
        int r = j / XF4PR, kc = j % XF4PR;
        int grow = row0 + r;
        float4 v = make_float4(0.f, 0.f, 0.f, 0.f);
        if (grow < n) v = ld4(A + (size_t)grow * K + kc * 4);
        *(float4*)&Xs[r * K + kc * 4] = v;
    }
    __syncthreads();

    int c0 = (tid & 15) * 4;
    int r0 = (tid >> 4) * 4;
    float4 acc[4] = {};
    #pragma unroll 4
    for (int kk = 0; kk < K; kk += 4) {
        float4 w0 = ld4(&Ws[(kk + 0) * 64 + c0]);
        float4 w1 = ld4(&Ws[(kk + 1) * 64 + c0]);
        float4 w2 = ld4(&Ws[(kk + 2) * 64 + c0]);
        float4 w3 = ld4(&Ws[(kk + 3) * 64 + c0]);
        #pragma unroll
        for (int i = 0; i < 4; i++) {
            float4 a = ld4(&Xs[(r0 + i) * K + kk]);
            acc[i].x = fmaf(a.x, w0.x, fmaf(a.y, w1.x, fmaf(a.z, w2.x, fmaf(a.w, w3.x, acc[i].x))));
            acc[i].y = fmaf(a.x, w0.y, fmaf(a.y, w1.y, fmaf(a.z, w2.y, fmaf(a.w, w3.y, acc[i].y))));
            acc[i].z = fmaf(a.x, w0.z, fmaf(a.y, w1.z, fmaf(a.z, w2.z, fmaf(a.w, w3.z, acc[i].z))));
            acc[i].w = fmaf(a.x, w0.w, fmaf(a.y, w1.w, fmaf(a.z, w2.w, fmaf(a.w, w3.w, acc[i].w))));
        }
    }
    #pragma unroll
    for (int i = 0; i < 4; i++) {
        int grow = row0 + r0 + i;
        if (grow < n) *(float4*)&out[(size_t)grow * 64 + c0] = acc[i];
    }
}

// -------------------- propagation (gather over CSR), one wave per node --------------------
// SPLIT_OUT: write [n,32]+[n,32] (mu | logvar) with separate biases; else write [n,64] (+ReLU).
template<bool RELU, bool SPLIT_OUT>
__global__ __launch_bounds__(256) void k_prop(const float* __restrict__ hin,
                                              const int* __restrict__ csr_src,
                                              const float* __restrict__ csr_norm,
                                              const int* __restrict__ rowptr,
                                              const int* __restrict__ cnt,
                                              const float* __restrict__ dinv,
                                              const float* __restrict__ bias0,
                                              const float* __restrict__ bias1,
                                              float* __restrict__ out, int n) {
    int node = blockIdx.x * 4 + (threadIdx.x >> 6);
    int c = threadIdx.x & 63;
    if (node >= n) return;
    float di = dinv[node];
    float acc = hin[(size_t)node * 64 + c] * di * di;   // self-loop, weight 1
    int beg = rowptr[node];
    int m = cnt[node];
    const int* sp = csr_src + beg;
    const float* np = csr_norm + beg;
    int e = 0;
    for (; e + 4 <= m; e += 4) {
        int s0 = sp[e], s1 = sp[e + 1], s2 = sp[e + 2], s3 = sp[e + 3];
        float n0 = np[e], n1 = np[e + 1], n2 = np[e + 2], n3 = np[e + 3];
        acc = fmaf(hin[(size_t)s0 * 64 + c], n0, acc);
        acc = fmaf(hin[(size_t)s1 * 64 + c], n1, acc);
        acc = fmaf(hin[(size_t)s2 * 64 + c], n2, acc);
        acc = fmaf(hin[(size_t)s3 * 64 + c], n3, acc);
    }
    for (; e < m; e++) acc = fmaf(hin[(size_t)sp[e] * 64 + c], np[e], acc);
    if (!SPLIT_OUT) {
        acc += bias0[c];
        if (RELU) acc = fmaxf(acc, 0.0f);
        out[(size_t)node * 64 + c] = acc;
    } else {
        if (c < 32) out[(size_t)node * 32 + c] = acc + bias0[c];
        else        out[(size_t)n * 32 + (size_t)node * 32 + (c - 32)] = acc + bias1[c - 32];
    }
}

// -------------------- launch --------------------
extern "C" void kernel_launch(void* const* d_in, const int* in_sizes, int n_in,
                              void* d_out, int out_size, void* d_ws, size_t ws_size,
                              hipStream_t stream) {
    const float* x   = (const float*)d_in[0];
    const int*   ei  = (const int*)d_in[1];   // [2, E] int32
    const float* ew  = (const float*)d_in[2];
    const float* W1  = (const float*)d_in[3];
    const float* b1  = (const float*)d_in[4];
    const float* Wmu = (const float*)d_in[5];
    const float* bmu = (const float*)d_in[6];
    const float* Wlv = (const float*)d_in[7];
    const float* blv = (const float*)d_in[8];
    float* outp = (float*)d_out;

    const int n = in_sizes[0] / 128;
    const int E = in_sizes[2];
    const int* src = ei;
    const int* dst = ei + E;

    // workspace layout
    size_t o = 0;
    auto alloc = [&](size_t bytes) { void* p = (char*)d_ws + o; o += (bytes + 511) & ~(size_t)511; return p; };
    float* deg      = (float*)alloc((size_t)n * 4);
    float* dinv     = (float*)alloc((size_t)n * 4);
    int*   cnt      = (int*)alloc((size_t)n * 4);
    int*   fill     = (int*)alloc((size_t)n * 4);
    int*   rowptr   = (int*)alloc((size_t)n * 4);
    int*   bsum     = (int*)alloc((size_t)((n + 255) / 256) * 4);
    int*   csr_src  = (int*)alloc((size_t)E * 4);
    float* csr_norm = (float*)alloc((size_t)E * 4);
    float* h0       = (float*)alloc((size_t)n * 64 * 4);
    float* h        = (float*)alloc((size_t)n * 64 * 4);
    float* hc       = h0;   // reuse: h0 dead after prop1

    const int nb_n = (n + 255) / 256;
    const int nb_e = (E + 255) / 256;

    k_init<<<nb_n, 256, 0, stream>>>(deg, cnt, fill, n);
    k_edge_count<<<nb_e, 256, 0, stream>>>(dst, ew, deg, cnt, E);
    k_dinv<<<nb_n, 256, 0, stream>>>(deg, dinv, n);
    k_scan_local<<<nb_n, 256, 0, stream>>>(cnt, rowptr, bsum, n);
    k_scan_bsum<<<1, 256, 0, stream>>>(bsum, nb_n);
    k_scan_add<<<nb_n, 256, 0, stream>>>(rowptr, bsum, n);
    k_scatter<<<nb_e, 256, 0, stream>>>(src, dst, ew, dinv, rowptr, fill, csr_src, csr_norm, E);

    const int gb = (n + 63) / 64;
    k_gemm<128, false><<<gb, 256, 0, stream>>>(x, W1, nullptr, h0, n);
    k_prop<true, false><<<(n + 3) / 4, 256, 0, stream>>>(h0, csr_src, csr_norm, rowptr, cnt, dinv,
                                                         b1, nullptr, h, n);
    k_gemm<64, true><<<gb, 256, 0, stream>>>(h, Wmu, Wlv, hc, n);
    k_prop<false, true><<<(n + 3) / 4, 256, 0, stream>>>(hc, csr_src, csr_norm, rowptr, cnt, dinv,
                                                         bmu, blv, outp, n);
}

// Round 2
// 475.129 us; speedup vs baseline: 1.1688x; 1.1688x over previous
//
#include <hip/hip_runtime.h>

#define NREP 8  // privatization replicas == XCD count (blockIdx % 8 heuristic)

// -------------------- helpers --------------------
static __device__ __forceinline__ float4 ld4(const float* p) { return *(const float4*)p; }

// -------------------- fused histogram: packed u64 atomic, 8-way privatized --------------------
// agg[r*n + d] accumulates: (count << 40) | fixed_point_32(ew). Per-node sum(ew) < 256 -> no carry.
__global__ __launch_bounds__(256) void k_count(const int* __restrict__ dst,
                                               const float* __restrict__ ew,
                                               unsigned long long* __restrict__ agg,
                                               int n, int E) {
    int e = blockIdx.x * 256 + threadIdx.x;
    if (e < E) {
        int d = dst[e];
        unsigned long long c = (1ull << 40) |
                               (unsigned long long)(ew[e] * 4294967296.0f);
        atomicAdd(&agg[(size_t)(blockIdx.x & (NREP - 1)) * n + d], c);
    }
}

// -------------------- reduce replicas: cnt, per-replica bases, deg -> dinv --------------------
__global__ __launch_bounds__(256) void k_reduce(const unsigned long long* __restrict__ agg,
                                                int* __restrict__ base,
                                                int* __restrict__ cnt,
                                                float* __restrict__ dinv, int n) {
    int i = blockIdx.x * 256 + threadIdx.x;
    if (i >= n) return;
    unsigned long long tot = 0;
    int pre = 0;
    #pragma unroll
    for (int r = 0; r < NREP; r++) {
        base[(size_t)r * n + i] = pre;
        unsigned long long v = agg[(size_t)r * n + i];
        tot += v;
        pre += (int)(v >> 40);
    }
    cnt[i] = (int)(tot >> 40);
    float s = (float)(tot & ((1ull << 40) - 1)) * (1.0f / 4294967296.0f);
    dinv[i] = rsqrtf(1.0f + s);   // self-loop weight 1 => deg >= 1
}

// -------------------- 3-phase exclusive scan over cnt -> rowptr --------------------
__global__ __launch_bounds__(256) void k_scan_local(const int* __restrict__ cnt,
                                                    int* __restrict__ rowptr,
                                                    int* __restrict__ bsum, int n) {
    __shared__ int s[256];
    int tid = threadIdx.x;
    int i = blockIdx.x * 256 + tid;
    int v = (i < n) ? cnt[i] : 0;
    s[tid] = v; __syncthreads();
    #pragma unroll
    for (int off = 1; off < 256; off <<= 1) {
        int t = (tid >= off) ? s[tid - off] : 0;
        __syncthreads();
        s[tid] += t;
        __syncthreads();
    }
    if (i < n) rowptr[i] = s[tid] - v;          // block-local exclusive
    if (tid == 255) bsum[blockIdx.x] = s[255];  // block total
}

__global__ __launch_bounds__(256) void k_scan_bsum(int* bsum, int nb) {
    __shared__ int s[256];
    __shared__ int run;
    int tid = threadIdx.x;
    if (tid == 0) run = 0;
    __syncthreads();
    for (int base = 0; base < nb; base += 256) {
        int v = (base + tid < nb) ? bsum[base + tid] : 0;
        s[tid] = v; __syncthreads();
        #pragma unroll
        for (int off = 1; off < 256; off <<= 1) {
            int t = (tid >= off) ? s[tid - off] : 0;
            __syncthreads();
            s[tid] += t;
            __syncthreads();
        }
        if (base + tid < nb) bsum[base + tid] = run + s[tid] - v;
        __syncthreads();
        if (tid == 0) run += s[255];
        __syncthreads();
    }
}

__global__ __launch_bounds__(256) void k_scan_add(int* __restrict__ rowptr,
                                                  const int* __restrict__ bsum, int n) {
    int i = blockIdx.x * 256 + threadIdx.x;
    if (i < n) rowptr[i] += bsum[blockIdx.x];
}

// -------------------- scatter edges into CSR (by dst), privatized fill counters --------------------
__global__ __launch_bounds__(256) void k_scatter(const int* __restrict__ src,
                                                 const int* __restrict__ dst,
                                                 const float* __restrict__ ew,
                                                 const float* __restrict__ dinv,
                                                 const int* __restrict__ rowptr,
                                                 const int* __restrict__ base,
                                                 int* fill,
                                                 int* __restrict__ csr_src,
                                                 float* __restrict__ csr_norm, int n, int E) {
    int e = blockIdx.x * 256 + threadIdx.x;
    if (e < E) {
        int s = src[e], d = dst[e];
        int r = blockIdx.x & (NREP - 1);
        int p = rowptr[d] + base[(size_t)r * n + d] + atomicAdd(&fill[(size_t)r * n + d], 1);
        csr_src[p] = s;
        csr_norm[p] = dinv[s] * ew[e] * dinv[d];
    }
}

// -------------------- GEMM: out[n,64] = A[n,K] @ W[K,64] --------------------
template<int K, bool SPLITW>
__global__ __launch_bounds__(256) void k_gemm(const float* __restrict__ A,
                                              const float* __restrict__ W0,
                                              const float* __restrict__ W1s,
                                              float* __restrict__ out, int n) {
    __shared__ float Ws[K * 64];
    __shared__ float Xs[64 * K];
    int tid = threadIdx.x;
    int row0 = blockIdx.x * 64;

    constexpr int WF4 = K * 64 / 4;
    for (int j = tid; j < WF4; j += 256) {
        float4 v;
        if (!SPLITW) {
            v = ld4(W0 + j * 4);
        } else {
            int k = (j * 4) >> 6;
            int c = (j * 4) & 63;
            v = (c < 32) ? ld4(W0 + k * 32 + c) : ld4(W1s + k * 32 + (c - 32));
        }
        *(float4*)&Ws[j * 4] = v;
    }
    constexpr int XF4PR = K / 4;
    for (int j = tid; j < 64 * XF4PR; j += 256) {
        int r = j / XF4PR, kc = j % XF4PR;
        int grow = row0 + r;
        float4 v = make_float4(0.f, 0.f, 0.f, 0.f);
        if (grow < n) v = ld4(A + (size_t)grow * K + kc * 4);
        *(float4*)&Xs[r * K + kc * 4] = v;
    }
    __syncthreads();

    int c0 = (tid & 15) * 4;
    int r0 = (tid >> 4) * 4;
    float4 acc[4] = {};
    #pragma unroll 4
    for (int kk = 0; kk < K; kk += 4) {
        float4 w0 = ld4(&Ws[(kk + 0) * 64 + c0]);
        float4 w1 = ld4(&Ws[(kk + 1) * 64 + c0]);
        float4 w2 = ld4(&Ws[(kk + 2) * 64 + c0]);
        float4 w3 = ld4(&Ws[(kk + 3) * 64 + c0]);
        #pragma unroll
        for (int i = 0; i < 4; i++) {
            float4 a = ld4(&Xs[(r0 + i) * K + kk]);
            acc[i].x = fmaf(a.x, w0.x, fmaf(a.y, w1.x, fmaf(a.z, w2.x, fmaf(a.w, w3.x, acc[i].x))));
            acc[i].y = fmaf(a.x, w0.y, fmaf(a.y, w1.y, fmaf(a.z, w2.y, fmaf(a.w, w3.y, acc[i].y))));
            acc[i].z = fmaf(a.x, w0.z, fmaf(a.y, w1.z, fmaf(a.z, w2.z, fmaf(a.w, w3.z, acc[i].z))));
            acc[i].w = fmaf(a.x, w0.w, fmaf(a.y, w1.w, fmaf(a.z, w2.w, fmaf(a.w, w3.w, acc[i].w))));
        }
    }
    #pragma unroll
    for (int i = 0; i < 4; i++) {
        int grow = row0 + r0 + i;
        if (grow < n) *(float4*)&out[(size_t)grow * 64 + c0] = acc[i];
    }
}

// -------------------- propagation (gather over CSR), one wave per node --------------------
template<bool RELU, bool SPLIT_OUT>
__global__ __launch_bounds__(256) void k_prop(const float* __restrict__ hin,
                                              const int* __restrict__ csr_src,
                                              const float* __restrict__ csr_norm,
                                              const int* __restrict__ rowptr,
                                              const int* __restrict__ cnt,
                                              const float* __restrict__ dinv,
                                              const float* __restrict__ bias0,
                                              const float* __restrict__ bias1,
                                              float* __restrict__ out, int n) {
    int node = blockIdx.x * 4 + (threadIdx.x >> 6);
    int c = threadIdx.x & 63;
    if (node >= n) return;
    float di = dinv[node];
    float acc = hin[(size_t)node * 64 + c] * di * di;   // self-loop, weight 1
    int beg = rowptr[node];
    int m = cnt[node];
    const int* sp = csr_src + beg;
    const float* np = csr_norm + beg;
    int e = 0;
    for (; e + 4 <= m; e += 4) {
        int s0 = sp[e], s1 = sp[e + 1], s2 = sp[e + 2], s3 = sp[e + 3];
        float n0 = np[e], n1 = np[e + 1], n2 = np[e + 2], n3 = np[e + 3];
        acc = fmaf(hin[(size_t)s0 * 64 + c], n0, acc);
        acc = fmaf(hin[(size_t)s1 * 64 + c], n1, acc);
        acc = fmaf(hin[(size_t)s2 * 64 + c], n2, acc);
        acc = fmaf(hin[(size_t)s3 * 64 + c], n3, acc);
    }
    for (; e < m; e++) acc = fmaf(hin[(size_t)sp[e] * 64 + c], np[e], acc);
    if (!SPLIT_OUT) {
        acc += bias0[c];
        if (RELU) acc = fmaxf(acc, 0.0f);
        out[(size_t)node * 64 + c] = acc;
    } else {
        if (c < 32) out[(size_t)node * 32 + c] = acc + bias0[c];
        else        out[(size_t)n * 32 + (size_t)node * 32 + (c - 32)] = acc + bias1[c - 32];
    }
}

// -------------------- launch --------------------
extern "C" void kernel_launch(void* const* d_in, const int* in_sizes, int n_in,
                              void* d_out, int out_size, void* d_ws, size_t ws_size,
                              hipStream_t stream) {
    const float* x   = (const float*)d_in[0];
    const int*   ei  = (const int*)d_in[1];   // [2, E]
    const float* ew  = (const float*)d_in[2];
    const float* W1  = (const float*)d_in[3];
    const float* b1  = (const float*)d_in[4];
    const float* Wmu = (const float*)d_in[5];
    const float* bmu = (const float*)d_in[6];
    const float* Wlv = (const float*)d_in[7];
    const float* blv = (const float*)d_in[8];
    float* outp = (float*)d_out;

    const int n = in_sizes[0] / 128;
    const int E = in_sizes[2];
    const int* src = ei;
    const int* dst = ei + E;

    // workspace layout
    size_t o = 0;
    auto alloc = [&](size_t bytes) { void* p = (char*)d_ws + o; o += (bytes + 511) & ~(size_t)511; return p; };
    size_t zbeg = o;
    unsigned long long* agg = (unsigned long long*)alloc((size_t)NREP * n * 8);
    int*   fill     = (int*)alloc((size_t)NREP * n * 4);
    size_t zend = o;                       // agg+fill zeroed with one memset
    int*   base     = (int*)alloc((size_t)NREP * n * 4);
    int*   cnt      = (int*)alloc((size_t)n * 4);
    float* dinv     = (float*)alloc((size_t)n * 4);
    int*   rowptr   = (int*)alloc((size_t)n * 4);
    int*   bsum     = (int*)alloc((size_t)((n + 255) / 256) * 4);
    int*   csr_src  = (int*)alloc((size_t)E * 4);
    float* csr_norm = (float*)alloc((size_t)E * 4);
    float* h0       = (float*)alloc((size_t)n * 64 * 4);
    float* h        = (float*)alloc((size_t)n * 64 * 4);
    float* hc       = h0;   // reuse: h0 dead after prop1

    const int nb_n = (n + 255) / 256;
    const int nb_e = (E + 255) / 256;

    hipMemsetAsync((char*)d_ws + zbeg, 0, zend - zbeg, stream);
    k_count<<<nb_e, 256, 0, stream>>>(dst, ew, agg, n, E);
    k_reduce<<<nb_n, 256, 0, stream>>>(agg, base, cnt, dinv, n);
    k_scan_local<<<nb_n, 256, 0, stream>>>(cnt, rowptr, bsum, n);
    k_scan_bsum<<<1, 256, 0, stream>>>(bsum, nb_n);
    k_scan_add<<<nb_n, 256, 0, stream>>>(rowptr, bsum, n);
    k_scatter<<<nb_e, 256, 0, stream>>>(src, dst, ew, dinv, rowptr, base, fill, csr_src, csr_norm, n, E);

    const int gb = (n + 63) / 64;
    k_gemm<128, false><<<gb, 256, 0, stream>>>(x, W1, nullptr, h0, n);
    k_prop<true, false><<<(n + 3) / 4, 256, 0, stream>>>(h0, csr_src, csr_norm, rowptr, cnt, dinv,
                                                         b1, nullptr, h, n);
    k_gemm<64, true><<<gb, 256, 0, stream>>>(h, Wmu, Wlv, hc, n);
    k_prop<false, true><<<(n + 3) / 4, 256, 0, stream>>>(hc, csr_src, csr_norm, rowptr, cnt, dinv,
                                                         bmu, blv, outp, n);
}

// Round 3
// 470.780 us; speedup vs baseline: 1.1796x; 1.0092x over previous
//
#include <hip/hip_runtime.h>

// -------------------- helpers --------------------
static __device__ __forceinline__ float4 ld4(const float* p) { return *(const float4*)p; }

// XCD-stripe bin for a dst node: 512-node stripes round-robin over 8 bins.
// Blocks with blockIdx%8==b process bin b only -> atomics/writes stay in one XCD's L2.
static __device__ __forceinline__ int dbin(int d) { return (d >> 9) & 7; }

// -------------------- fused histogram: packed u64 atomic, XCD-partitioned --------------------
// agg[d] accumulates (count << 40) | fixed_point_32(ew). Per-node sum(ew) < 256 -> no carry.
__global__ __launch_bounds__(256) void k_count(const int* __restrict__ dst,
                                               const float* __restrict__ ew,
                                               unsigned long long* __restrict__ agg,
                                               int E) {
    int e = (blockIdx.x >> 3) * 256 + threadIdx.x;
    int b = blockIdx.x & 7;
    if (e < E) {
        int d = dst[e];
        if (dbin(d) == b) {
            unsigned long long c = (1ull << 40) |
                                   (unsigned long long)(ew[e] * 4294967296.0f);
            atomicAdd(&agg[d], c);
        }
    }
}

// -------------------- unpack agg: cnt, dinv; zero fill --------------------
__global__ __launch_bounds__(256) void k_reduce(const unsigned long long* __restrict__ agg,
                                                int* __restrict__ cnt,
                                                int* __restrict__ fill,
                                                float* __restrict__ dinv, int n) {
    int i = blockIdx.x * 256 + threadIdx.x;
    if (i >= n) return;
    unsigned long long v = agg[i];
    cnt[i] = (int)(v >> 40);
    fill[i] = 0;
    float s = (float)(v & ((1ull << 40) - 1)) * (1.0f / 4294967296.0f);
    dinv[i] = rsqrtf(1.0f + s);   // self-loop weight 1 => deg >= 1
}

// -------------------- 3-phase exclusive scan over cnt -> rowptr --------------------
__global__ __launch_bounds__(256) void k_scan_local(const int* __restrict__ cnt,
                                                    int* __restrict__ rowptr,
                                                    int* __restrict__ bsum, int n) {
    __shared__ int s[256];
    int tid = threadIdx.x;
    int i = blockIdx.x * 256 + tid;
    int v = (i < n) ? cnt[i] : 0;
    s[tid] = v; __syncthreads();
    #pragma unroll
    for (int off = 1; off < 256; off <<= 1) {
        int t = (tid >= off) ? s[tid - off] : 0;
        __syncthreads();
        s[tid] += t;
        __syncthreads();
    }
    if (i < n) rowptr[i] = s[tid] - v;          // block-local exclusive
    if (tid == 255) bsum[blockIdx.x] = s[255];  // block total
}

__global__ __launch_bounds__(256) void k_scan_bsum(int* bsum, int nb) {
    __shared__ int s[256];
    __shared__ int run;
    int tid = threadIdx.x;
    if (tid == 0) run = 0;
    __syncthreads();
    for (int base = 0; base < nb; base += 256) {
        int v = (base + tid < nb) ? bsum[base + tid] : 0;
        s[tid] = v; __syncthreads();
        #pragma unroll
        for (int off = 1; off < 256; off <<= 1) {
            int t = (tid >= off) ? s[tid - off] : 0;
            __syncthreads();
            s[tid] += t;
            __syncthreads();
        }
        if (base + tid < nb) bsum[base + tid] = run + s[tid] - v;
        __syncthreads();
        if (tid == 0) run += s[255];
        __syncthreads();
    }
}

__global__ __launch_bounds__(256) void k_scan_add(int* __restrict__ rowptr,
                                                  const int* __restrict__ bsum, int n) {
    int i = blockIdx.x * 256 + threadIdx.x;
    if (i < n) rowptr[i] += bsum[blockIdx.x];
}

// -------------------- scatter edges into CSR (by dst), XCD-partitioned, packed u64 --------------------
__global__ __launch_bounds__(256) void k_scatter(const int* __restrict__ src,
                                                 const int* __restrict__ dst,
                                                 const float* __restrict__ ew,
                                                 const float* __restrict__ dinv,
                                                 const int* __restrict__ rowptr,
                                                 int* fill,
                                                 unsigned long long* __restrict__ csr,
                                                 int E) {
    int e = (blockIdx.x >> 3) * 256 + threadIdx.x;
    int b = blockIdx.x & 7;
    if (e < E) {
        int d = dst[e];
        if (dbin(d) == b) {
            int s = src[e];
            int p = rowptr[d] + atomicAdd(&fill[d], 1);
            float norm = dinv[s] * ew[e] * dinv[d];
            csr[p] = (unsigned long long)(unsigned)s |
                     ((unsigned long long)__float_as_uint(norm) << 32);
        }
    }
}

// -------------------- GEMM: out[n,64] = A[n,K] @ W[K,64] --------------------
template<int K, bool SPLITW>
__global__ __launch_bounds__(256) void k_gemm(const float* __restrict__ A,
                                              const float* __restrict__ W0,
                                              const float* __restrict__ W1s,
                                              float* __restrict__ out, int n) {
    __shared__ float Ws[K * 64];
    __shared__ float Xs[64 * K];
    int tid = threadIdx.x;
    int row0 = blockIdx.x * 64;

    constexpr int WF4 = K * 64 / 4;
    for (int j = tid; j < WF4; j += 256) {
        float4 v;
        if (!SPLITW) {
            v = ld4(W0 + j * 4);
        } else {
            int k = (j * 4) >> 6;
            int c = (j * 4) & 63;
            v = (c < 32) ? ld4(W0 + k * 32 + c) : ld4(W1s + k * 32 + (c - 32));
        }
        *(float4*)&Ws[j * 4] = v;
    }
    constexpr int XF4PR = K / 4;
    for (int j = tid; j < 64 * XF4PR; j += 256) {
        int r = j / XF4PR, kc = j % XF4PR;
        int grow = row0 + r;
        float4 v = make_float4(0.f, 0.f, 0.f, 0.f);
        if (grow < n) v = ld4(A + (size_t)grow * K + kc * 4);
        *(float4*)&Xs[r * K + kc * 4] = v;
    }
    __syncthreads();

    int c0 = (tid & 15) * 4;
    int r0 = (tid >> 4) * 4;
    float4 acc[4] = {};
    #pragma unroll 4
    for (int kk = 0; kk < K; kk += 4) {
        float4 w0 = ld4(&Ws[(kk + 0) * 64 + c0]);
        float4 w1 = ld4(&Ws[(kk + 1) * 64 + c0]);
        float4 w2 = ld4(&Ws[(kk + 2) * 64 + c0]);
        float4 w3 = ld4(&Ws[(kk + 3) * 64 + c0]);
        #pragma unroll
        for (int i = 0; i < 4; i++) {
            float4 a = ld4(&Xs[(r0 + i) * K + kk]);
            acc[i].x = fmaf(a.x, w0.x, fmaf(a.y, w1.x, fmaf(a.z, w2.x, fmaf(a.w, w3.x, acc[i].x))));
            acc[i].y = fmaf(a.x, w0.y, fmaf(a.y, w1.y, fmaf(a.z, w2.y, fmaf(a.w, w3.y, acc[i].y))));
            acc[i].z = fmaf(a.x, w0.z, fmaf(a.y, w1.z, fmaf(a.z, w2.z, fmaf(a.w, w3.z, acc[i].z))));
            acc[i].w = fmaf(a.x, w0.w, fmaf(a.y, w1.w, fmaf(a.z, w2.w, fmaf(a.w, w3.w, acc[i].w))));
        }
    }
    #pragma unroll
    for (int i = 0; i < 4; i++) {
        int grow = row0 + r0 + i;
        if (grow < n) *(float4*)&out[(size_t)grow * 64 + c0] = acc[i];
    }
}

// -------------------- propagation (gather over packed CSR), one wave per node --------------------
template<bool RELU, bool SPLIT_OUT>
__global__ __launch_bounds__(256) void k_prop(const float* __restrict__ hin,
                                              const int2* __restrict__ csr,
                                              const int* __restrict__ rowptr,
                                              const int* __restrict__ cnt,
                                              const float* __restrict__ dinv,
                                              const float* __restrict__ bias0,
                                              const float* __restrict__ bias1,
                                              float* __restrict__ out, int n) {
    int node = blockIdx.x * 4 + (threadIdx.x >> 6);
    int c = threadIdx.x & 63;
    if (node >= n) return;
    float di = dinv[node];
    float acc = hin[(size_t)node * 64 + c] * di * di;   // self-loop, weight 1
    const int2* ep = csr + rowptr[node];
    int m = cnt[node];
    int e = 0;
    for (; e + 4 <= m; e += 4) {
        int2 p0 = ep[e], p1 = ep[e + 1], p2 = ep[e + 2], p3 = ep[e + 3];
        acc = fmaf(hin[(size_t)p0.x * 64 + c], __int_as_float(p0.y), acc);
        acc = fmaf(hin[(size_t)p1.x * 64 + c], __int_as_float(p1.y), acc);
        acc = fmaf(hin[(size_t)p2.x * 64 + c], __int_as_float(p2.y), acc);
        acc = fmaf(hin[(size_t)p3.x * 64 + c], __int_as_float(p3.y), acc);
    }
    for (; e < m; e++) {
        int2 p = ep[e];
        acc = fmaf(hin[(size_t)p.x * 64 + c], __int_as_float(p.y), acc);
    }
    if (!SPLIT_OUT) {
        acc += bias0[c];
        if (RELU) acc = fmaxf(acc, 0.0f);
        out[(size_t)node * 64 + c] = acc;
    } else {
        if (c < 32) out[(size_t)node * 32 + c] = acc + bias0[c];
        else        out[(size_t)n * 32 + (size_t)node * 32 + (c - 32)] = acc + bias1[c - 32];
    }
}

// -------------------- launch --------------------
extern "C" void kernel_launch(void* const* d_in, const int* in_sizes, int n_in,
                              void* d_out, int out_size, void* d_ws, size_t ws_size,
                              hipStream_t stream) {
    const float* x   = (const float*)d_in[0];
    const int*   ei  = (const int*)d_in[1];   // [2, E]
    const float* ew  = (const float*)d_in[2];
    const float* W1  = (const float*)d_in[3];
    const float* b1  = (const float*)d_in[4];
    const float* Wmu = (const float*)d_in[5];
    const float* bmu = (const float*)d_in[6];
    const float* Wlv = (const float*)d_in[7];
    const float* blv = (const float*)d_in[8];
    float* outp = (float*)d_out;

    const int n = in_sizes[0] / 128;
    const int E = in_sizes[2];
    const int* src = ei;
    const int* dst = ei + E;

    // workspace layout
    size_t o = 0;
    auto alloc = [&](size_t bytes) { void* p = (char*)d_ws + o; o += (bytes + 511) & ~(size_t)511; return p; };
    unsigned long long* agg = (unsigned long long*)alloc((size_t)n * 8);   // memset to 0
    int*   fill     = (int*)alloc((size_t)n * 4);                          // zeroed in k_reduce
    int*   cnt      = (int*)alloc((size_t)n * 4);
    float* dinv     = (float*)alloc((size_t)n * 4);
    int*   rowptr   = (int*)alloc((size_t)n * 4);
    int*   bsum     = (int*)alloc((size_t)((n + 255) / 256) * 4);
    unsigned long long* csr = (unsigned long long*)alloc((size_t)E * 8);
    float* h0       = (float*)alloc((size_t)n * 64 * 4);
    float* h        = (float*)alloc((size_t)n * 64 * 4);
    float* hc       = h0;   // reuse: h0 dead after prop1

    const int nb_n = (n + 255) / 256;
    const int nchunk = (E + 255) / 256;

    hipMemsetAsync(agg, 0, (size_t)n * 8, stream);
    k_count<<<nchunk * 8, 256, 0, stream>>>(dst, ew, agg, E);
    k_reduce<<<nb_n, 256, 0, stream>>>(agg, cnt, fill, dinv, n);
    k_scan_local<<<nb_n, 256, 0, stream>>>(cnt, rowptr, bsum, n);
    k_scan_bsum<<<1, 256, 0, stream>>>(bsum, nb_n);
    k_scan_add<<<nb_n, 256, 0, stream>>>(rowptr, bsum, n);
    k_scatter<<<nchunk * 8, 256, 0, stream>>>(src, dst, ew, dinv, rowptr, fill, csr, E);

    const int gb = (n + 63) / 64;
    k_gemm<128, false><<<gb, 256, 0, stream>>>(x, W1, nullptr, h0, n);
    k_prop<true, false><<<(n + 3) / 4, 256, 0, stream>>>(h0, (const int2*)csr, rowptr, cnt, dinv,
                                                         b1, nullptr, h, n);
    k_gemm<64, true><<<gb, 256, 0, stream>>>(h, Wmu, Wlv, hc, n);
    k_prop<false, true><<<(n + 3) / 4, 256, 0, stream>>>(hc, (const int2*)csr, rowptr, cnt, dinv,
                                                         bmu, blv, outp, n);
}